// Round 9
// baseline (220.587 us; speedup 1.0000x reference)
//
#include <hip/hip_runtime.h>
#include <hip/hip_bf16.h>
#include <math.h>

#define N_NODES 100000
#define N_EDGES 600000
#define F1 128   // conv1 width
#define F2 64    // conv2 width

#define DEG_BLOCKS   ((N_EDGES + 255) / 256)           // 2344
#define CONVW_ELEMS  (128 * 128 + 128 * 64)
#define CONVW_BLOCKS ((CONVW_ELEMS + 255) / 256)       // 96
#define MG1_BLOCKS   ((N_NODES + 63) / 64)             // 1563

typedef __attribute__((ext_vector_type(8))) short bf16x8;
typedef __attribute__((ext_vector_type(4))) float f32x4;

__device__ inline short bfbits(float x) {
    __hip_bfloat16 h = __float2bfloat16(x);
    return *reinterpret_cast<short*>(&h);
}
__device__ inline float bf2f(short u) {
    unsigned int x = ((unsigned int)(unsigned short)u) << 16;
    return __uint_as_float(x);
}

// ---------------- fused: degree count || weight conversion ----------------

__global__ __launch_bounds__(256) void dc_kernel(const int* __restrict__ dst, int* __restrict__ deg,
                                                 const float* __restrict__ W1, const float* __restrict__ W2,
                                                 unsigned short* __restrict__ Wt1, unsigned short* __restrict__ Wt2) {
    if (blockIdx.x < DEG_BLOCKS) {
        int e = blockIdx.x * 256 + threadIdx.x;
        if (e < N_EDGES) atomicAdd(&deg[dst[e]], 1);
    } else {
        int i = (blockIdx.x - DEG_BLOCKS) * 256 + threadIdx.x;
        if (i < 128 * 128) {
            int k = i / 128, n = i % 128;
            Wt1[n * 128 + k] = (unsigned short)bfbits(W1[i]);
        } else if (i < CONVW_ELEMS) {
            int j = i - 128 * 128;
            int k = j / 64, n = j % 64;
            Wt2[n * 128 + k] = (unsigned short)bfbits(W2[j]);
        }
    }
}

// ---------------- fused: dinv + region alloc (wave scan + one atomic) + cur init ----------

__global__ void prep_kernel(const int* __restrict__ deg, int* __restrict__ counter,
                            float* __restrict__ dinv, int* __restrict__ off,
                            int* __restrict__ cur) {
    int i = blockIdx.x * blockDim.x + threadIdx.x;
    int d = (i < N_NODES) ? deg[i] : 0;
    if (i < N_NODES) dinv[i] = rsqrtf((float)(d + 1));   // +1 self-loop
    int incl = d;
    #pragma unroll
    for (int o = 1; o < 64; o <<= 1) {
        int v = __shfl_up(incl, o);
        if ((threadIdx.x & 63) >= o) incl += v;
    }
    int base = 0;
    if ((threadIdx.x & 63) == 63) base = atomicAdd(counter, incl);
    base = __shfl(base, 63);
    if (i < N_NODES) {
        int o = base + incl - d;
        off[i] = o;
        cur[i] = o;
    }
}

// ---------------- fused: MFMA GEMM layer-1 || CSR fill ----------------
// gemm C-write staged through LDS: 64 scalar VMEM stores -> 4 coalesced dwordx4.

__global__ __launch_bounds__(256) void mf_kernel(const float* __restrict__ X,
                                                 const unsigned short* __restrict__ Wt,
                                                 unsigned short* __restrict__ out,
                                                 const int* __restrict__ src, const int* __restrict__ dst,
                                                 const float* __restrict__ dinv,
                                                 int* __restrict__ cur, int2* __restrict__ csr) {
    __shared__ short Cs[64 * 136];   // 17.4KB, row stride 136 shorts (272B, 16B-aligned)
    const int tid = threadIdx.x;
    if (blockIdx.x >= MG1_BLOCKS) {
        int e = (blockIdx.x - MG1_BLOCKS) * 256 + tid;
        if (e < N_EDGES) {
            int s = src[e], d = dst[e];
            float w = dinv[s] * dinv[d];
            int pos = atomicAdd(&cur[d], 1);
            csr[pos] = make_int2(s, __float_as_int(w));
        }
        return;
    }

    constexpr int NT = 128 / 16;
    const int wid = tid >> 6;
    const int l   = tid & 63;
    const int l16 = l & 15;
    const int kg  = l >> 4;          // 0..3

    const int row = blockIdx.x * 64 + wid * 16 + l16;
    const int rowc = (row < N_NODES) ? row : (N_NODES - 1);

    bf16x8 a[4];
    const float* xp = X + (size_t)rowc * 128 + kg * 8;
    #pragma unroll
    for (int ks = 0; ks < 4; ks++) {
        const float4 v0 = *(const float4*)(xp + ks * 32);
        const float4 v1 = *(const float4*)(xp + ks * 32 + 4);
        bf16x8 t;
        t[0] = bfbits(v0.x); t[1] = bfbits(v0.y); t[2] = bfbits(v0.z); t[3] = bfbits(v0.w);
        t[4] = bfbits(v1.x); t[5] = bfbits(v1.y); t[6] = bfbits(v1.z); t[7] = bfbits(v1.w);
        a[ks] = t;
    }

    f32x4 acc[NT];
    #pragma unroll
    for (int t = 0; t < NT; t++) acc[t] = (f32x4){0.f, 0.f, 0.f, 0.f};

    #pragma unroll
    for (int t = 0; t < NT; t++) {
        const unsigned short* wp = Wt + (size_t)(t * 16 + l16) * 128 + kg * 8;
        #pragma unroll
        for (int ks = 0; ks < 4; ks++) {
            bf16x8 b = *(const bf16x8*)(wp + ks * 32);
            acc[t] = __builtin_amdgcn_mfma_f32_16x16x32_bf16(a[ks], b, acc[t], 0, 0, 0);
        }
    }

    // stage C in LDS (bank-swizzled column groups: tg = t ^ kg)
    #pragma unroll
    for (int t = 0; t < NT; t++) {
        const int tg = t ^ kg;
        #pragma unroll
        for (int r = 0; r < 4; r++)
            Cs[(wid * 16 + kg * 4 + r) * 136 + tg * 16 + l16] = bfbits(acc[t][r]);
    }
    __syncthreads();

    // coalesced write-back: 4 x bf16x8 per thread
    #pragma unroll
    for (int it = 0; it < 4; it++) {
        const int u  = it * 256 + tid;     // 0..1023
        const int rl = u >> 4;             // 0..63
        const int ch = u & 15;             // 0..15
        const int orow = blockIdx.x * 64 + rl;
        if (orow < N_NODES) {
            const int kgr = (rl >> 2) & 3;
            const int tg  = (ch >> 1) ^ kgr;
            bf16x8 vv = *(const bf16x8*)(&Cs[rl * 136 + tg * 16 + (ch & 1) * 8]);
            *(bf16x8*)(out + (size_t)orow * 128 + ch * 8) = vv;
        }
    }
}

// ---------------- MFMA GEMM (layer 2, bf16 in): out[N,64], LDS-staged C ----------------

__global__ __launch_bounds__(256) void mgemm2_kernel(const unsigned short* __restrict__ Xb,
                                                     const unsigned short* __restrict__ Wt,
                                                     unsigned short* __restrict__ out) {
    __shared__ short Cs[64 * 72];   // 9.2KB, row stride 72 shorts (144B, 16B-aligned)
    constexpr int NT = 64 / 16;
    const int tid = threadIdx.x;
    const int wid = tid >> 6;
    const int l   = tid & 63;
    const int l16 = l & 15;
    const int kg  = l >> 4;

    const int row = blockIdx.x * 64 + wid * 16 + l16;
    const int rowc = (row < N_NODES) ? row : (N_NODES - 1);

    bf16x8 a[4];
    const unsigned short* xb = Xb + (size_t)rowc * 128 + kg * 8;
    #pragma unroll
    for (int ks = 0; ks < 4; ks++) a[ks] = *(const bf16x8*)(xb + ks * 32);

    f32x4 acc[NT];
    #pragma unroll
    for (int t = 0; t < NT; t++) acc[t] = (f32x4){0.f, 0.f, 0.f, 0.f};

    #pragma unroll
    for (int t = 0; t < NT; t++) {
        const unsigned short* wp = Wt + (size_t)(t * 16 + l16) * 128 + kg * 8;
        #pragma unroll
        for (int ks = 0; ks < 4; ks++) {
            bf16x8 b = *(const bf16x8*)(wp + ks * 32);
            acc[t] = __builtin_amdgcn_mfma_f32_16x16x32_bf16(a[ks], b, acc[t], 0, 0, 0);
        }
    }

    #pragma unroll
    for (int t = 0; t < NT; t++) {
        const int tg = (t ^ kg) & 3;
        #pragma unroll
        for (int r = 0; r < 4; r++)
            Cs[(wid * 16 + kg * 4 + r) * 72 + tg * 16 + l16] = bfbits(acc[t][r]);
    }
    __syncthreads();

    #pragma unroll
    for (int it = 0; it < 2; it++) {
        const int u  = it * 256 + tid;     // 0..511
        const int rl = u >> 3;             // 0..63
        const int ch = u & 7;              // 0..7
        const int orow = blockIdx.x * 64 + rl;
        if (orow < N_NODES) {
            const int kgr = (rl >> 2) & 3;
            const int tg  = ((ch >> 1) ^ kgr) & 3;
            bf16x8 vv = *(const bf16x8*)(&Cs[rl * 72 + tg * 16 + (ch & 1) * 8]);
            *(bf16x8*)(out + (size_t)orow * 64 + ch * 8) = vv;
        }
    }
}

// ---------------- fused aggregation (bf16 in/out, f32 accum), batch-4, 2-deep chain ------

template<int F>
__global__ __launch_bounds__(256) void gather_kernel(const unsigned short* __restrict__ xw,
                                                     const float* __restrict__ dinv,
                                                     const int* __restrict__ off,
                                                     const int* __restrict__ deg,
                                                     const int2* __restrict__ csr,
                                                     const float* __restrict__ bias,
                                                     unsigned short* __restrict__ h) {
    constexpr int LANES = F / 8;        // bf16x8 lanes per node: 16 or 8
    constexpr int NPB = 256 / LANES;
    const int n = blockIdx.x * NPB + threadIdx.x / LANES;
    if (n >= N_NODES) return;
    const int c = threadIdx.x % LANES;

    const float dn = dinv[n];
    float acc[8];
    {
        const bf16x8 v = *(const bf16x8*)(xw + (size_t)n * F + c * 8);
        const float sl = dn * dn;
        #pragma unroll
        for (int i = 0; i < 8; i++) acc[i] = bf2f(v[i]) * sl;
    }

    const int e0 = off[n];
    const int e1 = e0 + deg[n];
    for (int j = e0; j < e1; j += 4) {
        float w[4]; bf16x8 v[4];
        #pragma unroll
        for (int u = 0; u < 4; u++) {
            const int jj = j + u;
            const int jc = (jj < e1) ? jj : (e1 - 1);
            const int2 ee = csr[jc];
            w[u] = (jj < e1) ? __int_as_float(ee.y) : 0.f;
            v[u] = *(const bf16x8*)(xw + (size_t)ee.x * F + c * 8);
        }
        #pragma unroll
        for (int u = 0; u < 4; u++) {
            #pragma unroll
            for (int i = 0; i < 8; i++) acc[i] += bf2f(v[u][i]) * w[u];
        }
    }

    bf16x8 o;
    #pragma unroll
    for (int i = 0; i < 8; i++) o[i] = bfbits(fmaxf(acc[i] + bias[c * 8 + i], 0.f));
    *(bf16x8*)(h + (size_t)n * F + c * 8) = o;
}

// ---------------- head: gelu(h2 @ Wh1 + bh1) @ Wh2 + bh2 -> sigmoid ----------------

__global__ __launch_bounds__(256) void head_kernel(const unsigned short* __restrict__ h2,
                                                   const float* __restrict__ Wh1,
                                                   const float* __restrict__ bh1,
                                                   const float* __restrict__ Wh2,
                                                   const float* __restrict__ bh2,
                                                   float* __restrict__ out) {
    __shared__ float W1s[64 * 16];
    __shared__ float h2s[16 * 64];
    __shared__ float W2s[16];
    __shared__ float b1s[16];
    const int tid = threadIdx.x;
    const int node0 = blockIdx.x * 16;

    ((float4*)W1s)[tid] = ((const float4*)Wh1)[tid];
    if (tid < 16) { W2s[tid] = Wh2[tid]; b1s[tid] = bh1[tid]; }
    if (tid < 128) {                       // 16 nodes x 8 bf16x8-chunks
        int node = node0 + tid / 8;
        int ch = tid % 8;
        if (node < N_NODES) {
            bf16x8 v = *(const bf16x8*)(h2 + (size_t)node * 64 + ch * 8);
            #pragma unroll
            for (int i = 0; i < 8; i++) h2s[(tid / 8) * 64 + ch * 8 + i] = bf2f(v[i]);
        } else {
            #pragma unroll
            for (int i = 0; i < 8; i++) h2s[(tid / 8) * 64 + ch * 8 + i] = 0.f;
        }
    }
    __syncthreads();

    const int l  = tid & 15;
    const int nl = tid >> 4;
    const int node = node0 + nl;

    float s = b1s[l];
    #pragma unroll 8
    for (int k = 0; k < 64; k++)
        s += h2s[nl * 64 + k] * W1s[k * 16 + l];
    float g = 0.5f * s * (1.f + erff(s * 0.70710678118654752f));
    float p = g * W2s[l];
    p += __shfl_xor(p, 1);
    p += __shfl_xor(p, 2);
    p += __shfl_xor(p, 4);
    p += __shfl_xor(p, 8);
    if (l == 0 && node < N_NODES) {
        float z = p + bh2[0];
        out[node] = 1.f / (1.f + expf(-z));
    }
}

// ---------------- launch ----------------

extern "C" void kernel_launch(void* const* d_in, const int* in_sizes, int n_in,
                              void* d_out, int out_size, void* d_ws, size_t ws_size,
                              hipStream_t stream) {
    const float* x   = (const float*)d_in[0];
    const int*   ei  = (const int*)d_in[1];
    const float* W1  = (const float*)d_in[2];
    const float* b1  = (const float*)d_in[3];
    const float* W2  = (const float*)d_in[4];
    const float* b2  = (const float*)d_in[5];
    const float* Wh1 = (const float*)d_in[6];
    const float* bh1 = (const float*)d_in[7];
    const float* Wh2 = (const float*)d_in[8];
    const float* bh2 = (const float*)d_in[9];
    float* out = (float*)d_out;

    const int* srcA = ei;             // edge_index[0]
    const int* dstA = ei + N_EDGES;   // edge_index[1]

    char* ws = (char*)d_ws;
    const size_t MB = 1u << 20;
    float* dinv    = (float*)(ws);                    // N f32
    int*   deg     = (int*)  (ws + MB / 2);           // N i32 (+1 counter)
    int*   counter = deg + N_NODES;                   // 1 i32
    int*   off     = (int*)  (ws + MB);               // N i32
    int*   cur     = (int*)  (ws + MB + MB / 2);      // N i32
    int2*  csr     = (int2*) (ws + 2 * MB);           // E int2 (4.8MB)
    unsigned short* Wt1 = (unsigned short*)(ws + 7 * MB);            // 128x128 bf16
    unsigned short* Wt2 = Wt1 + 128 * 128;                           // 64x128 bf16
    unsigned short* bufA = (unsigned short*)(ws + 8 * MB);           // xw1 (N x 128 bf16, 25.6MB)
    unsigned short* bufB = (unsigned short*)(ws + 34 * MB);          // h1  (N x 128 bf16)
    unsigned short* xw2  = bufA;                                     // N x 64 bf16
    unsigned short* h2   = bufA + (size_t)N_NODES * F2;              // N x 64 bf16

    // zero deg+counter; then (deg || convw); prep; (mgemm1 || fill)
    hipMemsetAsync(deg, 0, (N_NODES + 1) * sizeof(int), stream);
    dc_kernel<<<DEG_BLOCKS + CONVW_BLOCKS, 256, 0, stream>>>(dstA, deg, W1, W2, Wt1, Wt2);
    prep_kernel<<<(N_NODES + 255) / 256, 256, 0, stream>>>(deg, counter, dinv, off, cur);
    mf_kernel<<<MG1_BLOCKS + DEG_BLOCKS, 256, 0, stream>>>(x, Wt1, bufA, srcA, dstA, dinv, cur, csr);

    // layer 1 aggregation
    gather_kernel<128><<<(N_NODES * 16 + 255) / 256, 256, 0, stream>>>(bufA, dinv, off, deg, csr, b1, bufB);

    // layer 2
    mgemm2_kernel<<<(N_NODES + 63) / 64, 256, 0, stream>>>(bufB, Wt2, xw2);
    gather_kernel<64><<<(N_NODES * 8 + 255) / 256, 256, 0, stream>>>(xw2, dinv, off, deg, csr, b2, h2);

    // head
    head_kernel<<<(N_NODES + 15) / 16, 256, 0, stream>>>(h2, Wh1, bh1, Wh2, bh2, out);
}

// Round 10
// 214.029 us; speedup vs baseline: 1.0306x; 1.0306x over previous
//
#include <hip/hip_runtime.h>
#include <hip/hip_bf16.h>
#include <math.h>

#define N_NODES 100000
#define N_EDGES 600000
#define F1 128   // conv1 width
#define F2 64    // conv2 width

#define DEG_BLOCKS   ((N_EDGES + 255) / 256)           // 2344
#define CONVW_ELEMS  (128 * 128 + 128 * 64)
#define CONVW_BLOCKS ((CONVW_ELEMS + 255) / 256)       // 96
#define MG1_BLOCKS   ((N_NODES + 63) / 64)             // 1563

typedef __attribute__((ext_vector_type(8))) short bf16x8;
typedef __attribute__((ext_vector_type(4))) float f32x4;

__device__ inline short bfbits(float x) {
    __hip_bfloat16 h = __float2bfloat16(x);
    return *reinterpret_cast<short*>(&h);
}
__device__ inline float bf2f(short u) {
    unsigned int x = ((unsigned int)(unsigned short)u) << 16;
    return __uint_as_float(x);
}

// ---------------- fused: degree count || weight conversion ----------------

__global__ __launch_bounds__(256) void dc_kernel(const int* __restrict__ dst, int* __restrict__ deg,
                                                 const float* __restrict__ W1, const float* __restrict__ W2,
                                                 unsigned short* __restrict__ Wt1, unsigned short* __restrict__ Wt2) {
    if (blockIdx.x < DEG_BLOCKS) {
        int e = blockIdx.x * 256 + threadIdx.x;
        if (e < N_EDGES) atomicAdd(&deg[dst[e]], 1);
    } else {
        int i = (blockIdx.x - DEG_BLOCKS) * 256 + threadIdx.x;
        if (i < 128 * 128) {
            int k = i / 128, n = i % 128;
            Wt1[n * 128 + k] = (unsigned short)bfbits(W1[i]);
        } else if (i < CONVW_ELEMS) {
            int j = i - 128 * 128;
            int k = j / 64, n = j % 64;
            Wt2[n * 128 + k] = (unsigned short)bfbits(W2[j]);
        }
    }
}

// ---------------- fused: dinv + region alloc (wave scan + one atomic) + cur init ----------

__global__ void prep_kernel(const int* __restrict__ deg, int* __restrict__ counter,
                            float* __restrict__ dinv, int* __restrict__ off,
                            int* __restrict__ cur) {
    int i = blockIdx.x * blockDim.x + threadIdx.x;
    int d = (i < N_NODES) ? deg[i] : 0;
    if (i < N_NODES) dinv[i] = rsqrtf((float)(d + 1));   // +1 self-loop
    int incl = d;
    #pragma unroll
    for (int o = 1; o < 64; o <<= 1) {
        int v = __shfl_up(incl, o);
        if ((threadIdx.x & 63) >= o) incl += v;
    }
    int base = 0;
    if ((threadIdx.x & 63) == 63) base = atomicAdd(counter, incl);
    base = __shfl(base, 63);
    if (i < N_NODES) {
        int o = base + incl - d;
        off[i] = o;
        cur[i] = o;
    }
}

// ---------------- fused: MFMA GEMM layer-1 || CSR fill (interleaved blocks) ----------------
// First 2*MG1_BLOCKS blocks alternate gemm/fill so both latency streams co-occupy CUs.
// csr entry is 4B (src only) to halve cross-XCD writeback amplification.

__global__ __launch_bounds__(256) void mf_kernel(const float* __restrict__ X,
                                                 const unsigned short* __restrict__ Wt,
                                                 unsigned short* __restrict__ out,
                                                 const int* __restrict__ src, const int* __restrict__ dst,
                                                 int* __restrict__ cur, int* __restrict__ csr_src) {
    const int tid = threadIdx.x;
    const int b = blockIdx.x;
    int gemmIdx = -1, fillIdx = -1;
    if (b < 2 * MG1_BLOCKS) {
        if ((b & 1) == 0) gemmIdx = b >> 1; else fillIdx = b >> 1;
    } else {
        fillIdx = (b - 2 * MG1_BLOCKS) + MG1_BLOCKS;
    }

    if (fillIdx >= 0) {
        int e = fillIdx * 256 + tid;
        if (e < N_EDGES) {
            int s = src[e], d = dst[e];
            int pos = atomicAdd(&cur[d], 1);
            csr_src[pos] = s;
        }
        return;
    }

    constexpr int NT = 128 / 16;
    const int wid = tid >> 6;
    const int l   = tid & 63;
    const int l16 = l & 15;
    const int kg  = l >> 4;          // 0..3

    const int row = gemmIdx * 64 + wid * 16 + l16;
    const int rowc = (row < N_NODES) ? row : (N_NODES - 1);

    bf16x8 a[4];
    const float* xp = X + (size_t)rowc * 128 + kg * 8;
    #pragma unroll
    for (int ks = 0; ks < 4; ks++) {
        const float4 v0 = *(const float4*)(xp + ks * 32);
        const float4 v1 = *(const float4*)(xp + ks * 32 + 4);
        bf16x8 t;
        t[0] = bfbits(v0.x); t[1] = bfbits(v0.y); t[2] = bfbits(v0.z); t[3] = bfbits(v0.w);
        t[4] = bfbits(v1.x); t[5] = bfbits(v1.y); t[6] = bfbits(v1.z); t[7] = bfbits(v1.w);
        a[ks] = t;
    }

    f32x4 acc[NT];
    #pragma unroll
    for (int t = 0; t < NT; t++) acc[t] = (f32x4){0.f, 0.f, 0.f, 0.f};

    #pragma unroll
    for (int t = 0; t < NT; t++) {
        const unsigned short* wp = Wt + (size_t)(t * 16 + l16) * 128 + kg * 8;
        #pragma unroll
        for (int ks = 0; ks < 4; ks++) {
            bf16x8 bb = *(const bf16x8*)(wp + ks * 32);
            acc[t] = __builtin_amdgcn_mfma_f32_16x16x32_bf16(a[ks], bb, acc[t], 0, 0, 0);
        }
    }

    const int orow0 = gemmIdx * 64 + wid * 16 + kg * 4;
    #pragma unroll
    for (int t = 0; t < NT; t++) {
        #pragma unroll
        for (int r = 0; r < 4; r++) {
            const int orow = orow0 + r;
            if (orow < N_NODES)
                out[(size_t)orow * 128 + t * 16 + l16] = (unsigned short)bfbits(acc[t][r]);
        }
    }
}

// ---------------- MFMA GEMM (layer 2, bf16 in): out[N,64] ----------------

__global__ __launch_bounds__(256) void mgemm2_kernel(const unsigned short* __restrict__ Xb,
                                                     const unsigned short* __restrict__ Wt,
                                                     unsigned short* __restrict__ out) {
    constexpr int NT = 64 / 16;
    const int tid = threadIdx.x;
    const int wid = tid >> 6;
    const int l   = tid & 63;
    const int l16 = l & 15;
    const int kg  = l >> 4;

    const int row = blockIdx.x * 64 + wid * 16 + l16;
    const int rowc = (row < N_NODES) ? row : (N_NODES - 1);

    bf16x8 a[4];
    const unsigned short* xb = Xb + (size_t)rowc * 128 + kg * 8;
    #pragma unroll
    for (int ks = 0; ks < 4; ks++) a[ks] = *(const bf16x8*)(xb + ks * 32);

    f32x4 acc[NT];
    #pragma unroll
    for (int t = 0; t < NT; t++) acc[t] = (f32x4){0.f, 0.f, 0.f, 0.f};

    #pragma unroll
    for (int t = 0; t < NT; t++) {
        const unsigned short* wp = Wt + (size_t)(t * 16 + l16) * 128 + kg * 8;
        #pragma unroll
        for (int ks = 0; ks < 4; ks++) {
            bf16x8 bb = *(const bf16x8*)(wp + ks * 32);
            acc[t] = __builtin_amdgcn_mfma_f32_16x16x32_bf16(a[ks], bb, acc[t], 0, 0, 0);
        }
    }

    const int orow0 = blockIdx.x * 64 + wid * 16 + kg * 4;
    #pragma unroll
    for (int t = 0; t < NT; t++) {
        #pragma unroll
        for (int r = 0; r < 4; r++) {
            const int orow = orow0 + r;
            if (orow < N_NODES)
                out[(size_t)orow * 64 + t * 16 + l16] = (unsigned short)bfbits(acc[t][r]);
        }
    }
}

// ---------------- fused aggregation (bf16 in/out, f32 accum), batch-4, parallel dinv ------
// h[n] = relu(sum_{s} xw[s]*dinv[s]*dinv[n] + xw[n]*dinv[n]^2 + b)

template<int F>
__global__ __launch_bounds__(256) void gather_kernel(const unsigned short* __restrict__ xw,
                                                     const float* __restrict__ dinv,
                                                     const int* __restrict__ off,
                                                     const int* __restrict__ deg,
                                                     const int* __restrict__ csr_src,
                                                     const float* __restrict__ bias,
                                                     unsigned short* __restrict__ h) {
    constexpr int LANES = F / 8;        // bf16x8 lanes per node: 16 or 8
    constexpr int NPB = 256 / LANES;
    const int n = blockIdx.x * NPB + threadIdx.x / LANES;
    if (n >= N_NODES) return;
    const int c = threadIdx.x % LANES;

    const float dn = dinv[n];
    float acc[8];
    {
        const bf16x8 v = *(const bf16x8*)(xw + (size_t)n * F + c * 8);
        const float sl = dn * dn;
        #pragma unroll
        for (int i = 0; i < 8; i++) acc[i] = bf2f(v[i]) * sl;
    }

    const int e0 = off[n];
    const int e1 = e0 + deg[n];
    for (int j = e0; j < e1; j += 4) {
        int s[4];
        #pragma unroll
        for (int u = 0; u < 4; u++) {
            const int jj = j + u;
            const int jc = (jj < e1) ? jj : (e1 - 1);
            s[u] = csr_src[jc];
        }
        float w[4]; bf16x8 v[4];
        #pragma unroll
        for (int u = 0; u < 4; u++) {
            w[u] = (j + u < e1) ? dinv[s[u]] * dn : 0.f;
            v[u] = *(const bf16x8*)(xw + (size_t)s[u] * F + c * 8);
        }
        #pragma unroll
        for (int u = 0; u < 4; u++) {
            #pragma unroll
            for (int i = 0; i < 8; i++) acc[i] += bf2f(v[u][i]) * w[u];
        }
    }

    bf16x8 o;
    #pragma unroll
    for (int i = 0; i < 8; i++) o[i] = bfbits(fmaxf(acc[i] + bias[c * 8 + i], 0.f));
    *(bf16x8*)(h + (size_t)n * F + c * 8) = o;
}

// ---------------- head: gelu(h2 @ Wh1 + bh1) @ Wh2 + bh2 -> sigmoid ----------------

__global__ __launch_bounds__(256) void head_kernel(const unsigned short* __restrict__ h2,
                                                   const float* __restrict__ Wh1,
                                                   const float* __restrict__ bh1,
                                                   const float* __restrict__ Wh2,
                                                   const float* __restrict__ bh2,
                                                   float* __restrict__ out) {
    __shared__ float W1s[64 * 16];
    __shared__ float h2s[16 * 64];
    __shared__ float W2s[16];
    __shared__ float b1s[16];
    const int tid = threadIdx.x;
    const int node0 = blockIdx.x * 16;

    ((float4*)W1s)[tid] = ((const float4*)Wh1)[tid];
    if (tid < 16) { W2s[tid] = Wh2[tid]; b1s[tid] = bh1[tid]; }
    if (tid < 128) {                       // 16 nodes x 8 bf16x8-chunks
        int node = node0 + tid / 8;
        int ch = tid % 8;
        if (node < N_NODES) {
            bf16x8 v = *(const bf16x8*)(h2 + (size_t)node * 64 + ch * 8);
            #pragma unroll
            for (int i = 0; i < 8; i++) h2s[(tid / 8) * 64 + ch * 8 + i] = bf2f(v[i]);
        } else {
            #pragma unroll
            for (int i = 0; i < 8; i++) h2s[(tid / 8) * 64 + ch * 8 + i] = 0.f;
        }
    }
    __syncthreads();

    const int l  = tid & 15;
    const int nl = tid >> 4;
    const int node = node0 + nl;

    float s = b1s[l];
    #pragma unroll 8
    for (int k = 0; k < 64; k++)
        s += h2s[nl * 64 + k] * W1s[k * 16 + l];
    float g = 0.5f * s * (1.f + erff(s * 0.70710678118654752f));
    float p = g * W2s[l];
    p += __shfl_xor(p, 1);
    p += __shfl_xor(p, 2);
    p += __shfl_xor(p, 4);
    p += __shfl_xor(p, 8);
    if (l == 0 && node < N_NODES) {
        float z = p + bh2[0];
        out[node] = 1.f / (1.f + expf(-z));
    }
}

// ---------------- launch ----------------

extern "C" void kernel_launch(void* const* d_in, const int* in_sizes, int n_in,
                              void* d_out, int out_size, void* d_ws, size_t ws_size,
                              hipStream_t stream) {
    const float* x   = (const float*)d_in[0];
    const int*   ei  = (const int*)d_in[1];
    const float* W1  = (const float*)d_in[2];
    const float* b1  = (const float*)d_in[3];
    const float* W2  = (const float*)d_in[4];
    const float* b2  = (const float*)d_in[5];
    const float* Wh1 = (const float*)d_in[6];
    const float* bh1 = (const float*)d_in[7];
    const float* Wh2 = (const float*)d_in[8];
    const float* bh2 = (const float*)d_in[9];
    float* out = (float*)d_out;

    const int* srcA = ei;             // edge_index[0]
    const int* dstA = ei + N_EDGES;   // edge_index[1]

    char* ws = (char*)d_ws;
    const size_t MB = 1u << 20;
    float* dinv    = (float*)(ws);                    // N f32
    int*   deg     = (int*)  (ws + MB / 2);           // N i32 (+1 counter)
    int*   counter = deg + N_NODES;                   // 1 i32
    int*   off     = (int*)  (ws + MB);               // N i32
    int*   cur     = (int*)  (ws + MB + MB / 2);      // N i32
    int*   csr_src = (int*)  (ws + 2 * MB);           // E i32 (2.4MB)
    unsigned short* Wt1 = (unsigned short*)(ws + 7 * MB);            // 128x128 bf16
    unsigned short* Wt2 = Wt1 + 128 * 128;                           // 64x128 bf16
    unsigned short* bufA = (unsigned short*)(ws + 8 * MB);           // xw1 (N x 128 bf16, 25.6MB)
    unsigned short* bufB = (unsigned short*)(ws + 34 * MB);          // h1  (N x 128 bf16)
    unsigned short* xw2  = bufA;                                     // N x 64 bf16
    unsigned short* h2   = bufA + (size_t)N_NODES * F2;              // N x 64 bf16

    // zero deg+counter; then (deg || convw); prep; (mgemm1 || fill)
    hipMemsetAsync(deg, 0, (N_NODES + 1) * sizeof(int), stream);
    dc_kernel<<<DEG_BLOCKS + CONVW_BLOCKS, 256, 0, stream>>>(dstA, deg, W1, W2, Wt1, Wt2);
    prep_kernel<<<(N_NODES + 255) / 256, 256, 0, stream>>>(deg, counter, dinv, off, cur);
    mf_kernel<<<MG1_BLOCKS + DEG_BLOCKS, 256, 0, stream>>>(x, Wt1, bufA, srcA, dstA, cur, csr_src);

    // layer 1 aggregation
    gather_kernel<128><<<(N_NODES * 16 + 255) / 256, 256, 0, stream>>>(bufA, dinv, off, deg, csr_src, b1, bufB);

    // layer 2
    mgemm2_kernel<<<(N_NODES + 63) / 64, 256, 0, stream>>>(bufB, Wt2, xw2);
    gather_kernel<64><<<(N_NODES * 8 + 255) / 256, 256, 0, stream>>>(xw2, dinv, off, deg, csr_src, b2, h2);

    // head
    head_kernel<<<(N_NODES + 15) / 16, 256, 0, stream>>>(h2, Wh1, bh1, Wh2, bh2, out);
}

// Round 11
// 213.485 us; speedup vs baseline: 1.0333x; 1.0025x over previous
//
#include <hip/hip_runtime.h>
#include <hip/hip_bf16.h>
#include <math.h>

#define N_NODES 100000
#define N_EDGES 600000
#define F1 128   // conv1 width
#define F2 64    // conv2 width

#define DEG_BLOCKS   ((N_EDGES + 255) / 256)           // 2344
#define CONVW_ELEMS  (128 * 128 + 128 * 64)
#define CONVW_BLOCKS ((CONVW_ELEMS + 255) / 256)       // 96
#define MG1_BLOCKS   ((N_NODES + 63) / 64)             // 1563

typedef __attribute__((ext_vector_type(8))) short bf16x8;
typedef __attribute__((ext_vector_type(4))) float f32x4;

__device__ inline short bfbits(float x) {
    __hip_bfloat16 h = __float2bfloat16(x);
    return *reinterpret_cast<short*>(&h);
}
__device__ inline float bf2f(short u) {
    unsigned int x = ((unsigned int)(unsigned short)u) << 16;
    return __uint_as_float(x);
}

// ---------------- fused: degree count || weight conversion ----------------

__global__ __launch_bounds__(256) void dc_kernel(const int* __restrict__ dst, int* __restrict__ deg,
                                                 const float* __restrict__ W1, const float* __restrict__ W2,
                                                 unsigned short* __restrict__ Wt1, unsigned short* __restrict__ Wt2) {
    if (blockIdx.x < DEG_BLOCKS) {
        int e = blockIdx.x * 256 + threadIdx.x;
        if (e < N_EDGES) atomicAdd(&deg[dst[e]], 1);
    } else {
        int i = (blockIdx.x - DEG_BLOCKS) * 256 + threadIdx.x;
        if (i < 128 * 128) {
            int k = i / 128, n = i % 128;
            Wt1[n * 128 + k] = (unsigned short)bfbits(W1[i]);
        } else if (i < CONVW_ELEMS) {
            int j = i - 128 * 128;
            int k = j / 64, n = j % 64;
            Wt2[n * 128 + k] = (unsigned short)bfbits(W2[j]);
        }
    }
}

// ---------------- fused: dinv + region alloc (wave scan + one atomic) + cur init ----------

__global__ void prep_kernel(const int* __restrict__ deg, int* __restrict__ counter,
                            float* __restrict__ dinv, int* __restrict__ off,
                            int* __restrict__ cur) {
    int i = blockIdx.x * blockDim.x + threadIdx.x;
    int d = (i < N_NODES) ? deg[i] : 0;
    if (i < N_NODES) dinv[i] = rsqrtf((float)(d + 1));   // +1 self-loop
    int incl = d;
    #pragma unroll
    for (int o = 1; o < 64; o <<= 1) {
        int v = __shfl_up(incl, o);
        if ((threadIdx.x & 63) >= o) incl += v;
    }
    int base = 0;
    if ((threadIdx.x & 63) == 63) base = atomicAdd(counter, incl);
    base = __shfl(base, 63);
    if (i < N_NODES) {
        int o = base + incl - d;
        off[i] = o;
        cur[i] = o;
    }
}

// ---------------- fused: MFMA GEMM layer-1 (C^T operand swap) || CSR fill ----------------
// gemm: D = mfma(Wt_frag, X_frag) gives C^T in regs; each thread owns ONE output row and
// 4 consecutive cols per tile -> packed 8B stores, single bounds check.

__global__ __launch_bounds__(256) void mf_kernel(const float* __restrict__ X,
                                                 const unsigned short* __restrict__ Wt,
                                                 unsigned short* __restrict__ out,
                                                 const int* __restrict__ src, const int* __restrict__ dst,
                                                 int* __restrict__ cur, int* __restrict__ csr_src) {
    const int tid = threadIdx.x;
    if (blockIdx.x >= MG1_BLOCKS) {
        int e = (blockIdx.x - MG1_BLOCKS) * 256 + tid;
        if (e < N_EDGES) {
            int s = src[e], d = dst[e];
            int pos = atomicAdd(&cur[d], 1);
            csr_src[pos] = s;
        }
        return;
    }

    constexpr int NT = 128 / 16;
    const int wid = tid >> 6;
    const int l   = tid & 63;
    const int l16 = l & 15;
    const int kg  = l >> 4;          // 0..3

    const int row = blockIdx.x * 64 + wid * 16 + l16;
    const int rowc = (row < N_NODES) ? row : (N_NODES - 1);

    bf16x8 a[4];
    const float* xp = X + (size_t)rowc * 128 + kg * 8;
    #pragma unroll
    for (int ks = 0; ks < 4; ks++) {
        const float4 v0 = *(const float4*)(xp + ks * 32);
        const float4 v1 = *(const float4*)(xp + ks * 32 + 4);
        bf16x8 t;
        t[0] = bfbits(v0.x); t[1] = bfbits(v0.y); t[2] = bfbits(v0.z); t[3] = bfbits(v0.w);
        t[4] = bfbits(v1.x); t[5] = bfbits(v1.y); t[6] = bfbits(v1.z); t[7] = bfbits(v1.w);
        a[ks] = t;
    }

    f32x4 acc[NT];
    #pragma unroll
    for (int t = 0; t < NT; t++) acc[t] = (f32x4){0.f, 0.f, 0.f, 0.f};

    #pragma unroll
    for (int t = 0; t < NT; t++) {
        const unsigned short* wp = Wt + (size_t)(t * 16 + l16) * 128 + kg * 8;
        #pragma unroll
        for (int ks = 0; ks < 4; ks++) {
            bf16x8 bb = *(const bf16x8*)(wp + ks * 32);
            acc[t] = __builtin_amdgcn_mfma_f32_16x16x32_bf16(bb, a[ks], acc[t], 0, 0, 0);
        }
    }

    // C^T layout: this thread owns row `row`, cols {t*16 + kg*4 + r}
    if (row < N_NODES) {
        #pragma unroll
        for (int t = 0; t < NT; t++) {
            short4 pk;
            pk.x = bfbits(acc[t][0]); pk.y = bfbits(acc[t][1]);
            pk.z = bfbits(acc[t][2]); pk.w = bfbits(acc[t][3]);
            *(short4*)(out + (size_t)row * 128 + t * 16 + kg * 4) = pk;
        }
    }
}

// ---------------- MFMA GEMM (layer 2, bf16 in, C^T swap): out[N,64] ----------------

__global__ __launch_bounds__(256) void mgemm2_kernel(const unsigned short* __restrict__ Xb,
                                                     const unsigned short* __restrict__ Wt,
                                                     unsigned short* __restrict__ out) {
    constexpr int NT = 64 / 16;
    const int tid = threadIdx.x;
    const int wid = tid >> 6;
    const int l   = tid & 63;
    const int l16 = l & 15;
    const int kg  = l >> 4;

    const int row = blockIdx.x * 64 + wid * 16 + l16;
    const int rowc = (row < N_NODES) ? row : (N_NODES - 1);

    bf16x8 a[4];
    const unsigned short* xb = Xb + (size_t)rowc * 128 + kg * 8;
    #pragma unroll
    for (int ks = 0; ks < 4; ks++) a[ks] = *(const bf16x8*)(xb + ks * 32);

    f32x4 acc[NT];
    #pragma unroll
    for (int t = 0; t < NT; t++) acc[t] = (f32x4){0.f, 0.f, 0.f, 0.f};

    #pragma unroll
    for (int t = 0; t < NT; t++) {
        const unsigned short* wp = Wt + (size_t)(t * 16 + l16) * 128 + kg * 8;
        #pragma unroll
        for (int ks = 0; ks < 4; ks++) {
            bf16x8 bb = *(const bf16x8*)(wp + ks * 32);
            acc[t] = __builtin_amdgcn_mfma_f32_16x16x32_bf16(bb, a[ks], acc[t], 0, 0, 0);
        }
    }

    if (row < N_NODES) {
        #pragma unroll
        for (int t = 0; t < NT; t++) {
            short4 pk;
            pk.x = bfbits(acc[t][0]); pk.y = bfbits(acc[t][1]);
            pk.z = bfbits(acc[t][2]); pk.w = bfbits(acc[t][3]);
            *(short4*)(out + (size_t)row * 64 + t * 16 + kg * 4) = pk;
        }
    }
}

// ---------------- fused aggregation (bf16 in/out, f32 accum), batch-4 ----------------
// h[n] = relu(sum_{s} xw[s]*dinv[s]*dinv[n] + xw[n]*dinv[n]^2 + b)

template<int F>
__global__ __launch_bounds__(256) void gather_kernel(const unsigned short* __restrict__ xw,
                                                     const float* __restrict__ dinv,
                                                     const int* __restrict__ off,
                                                     const int* __restrict__ deg,
                                                     const int* __restrict__ csr_src,
                                                     const float* __restrict__ bias,
                                                     unsigned short* __restrict__ h) {
    constexpr int LANES = F / 8;        // bf16x8 lanes per node: 16 or 8
    constexpr int NPB = 256 / LANES;
    const int n = blockIdx.x * NPB + threadIdx.x / LANES;
    if (n >= N_NODES) return;
    const int c = threadIdx.x % LANES;

    const float dn = dinv[n];
    float acc[8];
    {
        const bf16x8 v = *(const bf16x8*)(xw + (size_t)n * F + c * 8);
        const float sl = dn * dn;
        #pragma unroll
        for (int i = 0; i < 8; i++) acc[i] = bf2f(v[i]) * sl;
    }

    const int e0 = off[n];
    const int e1 = e0 + deg[n];
    for (int j = e0; j < e1; j += 4) {
        int s[4];
        #pragma unroll
        for (int u = 0; u < 4; u++) {
            const int jj = j + u;
            const int jc = (jj < e1) ? jj : (e1 - 1);
            s[u] = csr_src[jc];
        }
        float w[4]; bf16x8 v[4];
        #pragma unroll
        for (int u = 0; u < 4; u++) {
            w[u] = (j + u < e1) ? dinv[s[u]] * dn : 0.f;
            v[u] = *(const bf16x8*)(xw + (size_t)s[u] * F + c * 8);
        }
        #pragma unroll
        for (int u = 0; u < 4; u++) {
            #pragma unroll
            for (int i = 0; i < 8; i++) acc[i] += bf2f(v[u][i]) * w[u];
        }
    }

    bf16x8 o;
    #pragma unroll
    for (int i = 0; i < 8; i++) o[i] = bfbits(fmaxf(acc[i] + bias[c * 8 + i], 0.f));
    *(bf16x8*)(h + (size_t)n * F + c * 8) = o;
}

// ---------------- head: gelu(h2 @ Wh1 + bh1) @ Wh2 + bh2 -> sigmoid ----------------

__global__ __launch_bounds__(256) void head_kernel(const unsigned short* __restrict__ h2,
                                                   const float* __restrict__ Wh1,
                                                   const float* __restrict__ bh1,
                                                   const float* __restrict__ Wh2,
                                                   const float* __restrict__ bh2,
                                                   float* __restrict__ out) {
    __shared__ float W1s[64 * 16];
    __shared__ float h2s[16 * 64];
    __shared__ float W2s[16];
    __shared__ float b1s[16];
    const int tid = threadIdx.x;
    const int node0 = blockIdx.x * 16;

    ((float4*)W1s)[tid] = ((const float4*)Wh1)[tid];
    if (tid < 16) { W2s[tid] = Wh2[tid]; b1s[tid] = bh1[tid]; }
    if (tid < 128) {                       // 16 nodes x 8 bf16x8-chunks
        int node = node0 + tid / 8;
        int ch = tid % 8;
        if (node < N_NODES) {
            bf16x8 v = *(const bf16x8*)(h2 + (size_t)node * 64 + ch * 8);
            #pragma unroll
            for (int i = 0; i < 8; i++) h2s[(tid / 8) * 64 + ch * 8 + i] = bf2f(v[i]);
        } else {
            #pragma unroll
            for (int i = 0; i < 8; i++) h2s[(tid / 8) * 64 + ch * 8 + i] = 0.f;
        }
    }
    __syncthreads();

    const int l  = tid & 15;
    const int nl = tid >> 4;
    const int node = node0 + nl;

    float s = b1s[l];
    #pragma unroll 8
    for (int k = 0; k < 64; k++)
        s += h2s[nl * 64 + k] * W1s[k * 16 + l];
    float g = 0.5f * s * (1.f + erff(s * 0.70710678118654752f));
    float p = g * W2s[l];
    p += __shfl_xor(p, 1);
    p += __shfl_xor(p, 2);
    p += __shfl_xor(p, 4);
    p += __shfl_xor(p, 8);
    if (l == 0 && node < N_NODES) {
        float z = p + bh2[0];
        out[node] = 1.f / (1.f + expf(-z));
    }
}

// ---------------- launch ----------------

extern "C" void kernel_launch(void* const* d_in, const int* in_sizes, int n_in,
                              void* d_out, int out_size, void* d_ws, size_t ws_size,
                              hipStream_t stream) {
    const float* x   = (const float*)d_in[0];
    const int*   ei  = (const int*)d_in[1];
    const float* W1  = (const float*)d_in[2];
    const float* b1  = (const float*)d_in[3];
    const float* W2  = (const float*)d_in[4];
    const float* b2  = (const float*)d_in[5];
    const float* Wh1 = (const float*)d_in[6];
    const float* bh1 = (const float*)d_in[7];
    const float* Wh2 = (const float*)d_in[8];
    const float* bh2 = (const float*)d_in[9];
    float* out = (float*)d_out;

    const int* srcA = ei;             // edge_index[0]
    const int* dstA = ei + N_EDGES;   // edge_index[1]

    char* ws = (char*)d_ws;
    const size_t MB = 1u << 20;
    float* dinv    = (float*)(ws);                    // N f32
    int*   deg     = (int*)  (ws + MB / 2);           // N i32 (+1 counter)
    int*   counter = deg + N_NODES;                   // 1 i32
    int*   off     = (int*)  (ws + MB);               // N i32
    int*   cur     = (int*)  (ws + MB + MB / 2);      // N i32
    int*   csr_src = (int*)  (ws + 2 * MB);           // E i32 (2.4MB)
    unsigned short* Wt1 = (unsigned short*)(ws + 7 * MB);            // 128x128 bf16
    unsigned short* Wt2 = Wt1 + 128 * 128;                           // 64x128 bf16
    unsigned short* bufA = (unsigned short*)(ws + 8 * MB);           // xw1 (N x 128 bf16, 25.6MB)
    unsigned short* bufB = (unsigned short*)(ws + 34 * MB);          // h1  (N x 128 bf16)
    unsigned short* xw2  = bufA;                                     // N x 64 bf16
    unsigned short* h2   = bufA + (size_t)N_NODES * F2;              // N x 64 bf16

    // zero deg+counter; then (deg || convw); prep; (mgemm1 || fill)
    hipMemsetAsync(deg, 0, (N_NODES + 1) * sizeof(int), stream);
    dc_kernel<<<DEG_BLOCKS + CONVW_BLOCKS, 256, 0, stream>>>(dstA, deg, W1, W2, Wt1, Wt2);
    prep_kernel<<<(N_NODES + 255) / 256, 256, 0, stream>>>(deg, counter, dinv, off, cur);
    mf_kernel<<<MG1_BLOCKS + DEG_BLOCKS, 256, 0, stream>>>(x, Wt1, bufA, srcA, dstA, cur, csr_src);

    // layer 1 aggregation
    gather_kernel<128><<<(N_NODES * 16 + 255) / 256, 256, 0, stream>>>(bufA, dinv, off, deg, csr_src, b1, bufB);

    // layer 2
    mgemm2_kernel<<<(N_NODES + 63) / 64, 256, 0, stream>>>(bufB, Wt2, xw2);
    gather_kernel<64><<<(N_NODES * 8 + 255) / 256, 256, 0, stream>>>(xw2, dinv, off, deg, csr_src, b2, h2);

    // head
    head_kernel<<<(N_NODES + 15) / 16, 256, 0, stream>>>(h2, Wh1, bh1, Wh2, bh2, out);
}